// Round 1
// baseline (1132.538 us; speedup 1.0000x reference)
//
#include <hip/hip_runtime.h>

#define IN_DIM 128
#define HID 64

// ---------------- degree / normalization ----------------

__global__ __launch_bounds__(256) void k_deg(const int* __restrict__ dst,
                                             float* __restrict__ deg, int E) {
    int e = blockIdx.x * 256 + threadIdx.x;
    if (e < E) atomicAdd(&deg[dst[e]], 1.0f);
}

__global__ __launch_bounds__(256) void k_dis(float* __restrict__ dis, int N) {
    int i = blockIdx.x * 256 + threadIdx.x;
    if (i < N) dis[i] = rsqrtf(dis[i] + 1.0f);
}

// ---------------- dense transform: H[N,64] = X[N,K] @ W[K,64] ----------------

template <int K>
__global__ __launch_bounds__(256) void k_mm64(const float* __restrict__ X,
                                              const float* __restrict__ W,
                                              float* __restrict__ H, int N) {
    __shared__ float Ws[K * 64];
    __shared__ float Xs[4][K];
    for (int i = threadIdx.x; i < K * 64; i += 256) Ws[i] = W[i];
    int row0 = blockIdx.x * 4;
    for (int i = threadIdx.x; i < 4 * K; i += 256) {
        int r = i / K, k = i - r * K;
        int row = row0 + r;
        Xs[r][k] = (row < N) ? X[row * K + k] : 0.0f;
    }
    __syncthreads();
    int r = threadIdx.x >> 6;   // 0..3
    int c = threadIdx.x & 63;   // 0..63
    int row = row0 + r;
    if (row >= N) return;
    float acc = 0.0f;
#pragma unroll
    for (int k = 0; k < K; ++k) acc += Xs[r][k] * Ws[k * 64 + c];
    H[row * 64 + c] = acc;
}

// ---------------- agg init with self-loop + bias ----------------

__global__ __launch_bounds__(256) void k_self_init(const float* __restrict__ H,
                                                   const float* __restrict__ dis,
                                                   const float* __restrict__ b,
                                                   float* __restrict__ Agg, int N) {
    int idx = blockIdx.x * 256 + threadIdx.x;
    if (idx >= N * 64) return;
    int i = idx >> 6, f = idx & 63;
    float d = dis[i];
    Agg[idx] = H[idx] * d * d + b[f];
}

// ---------------- edge scatter: wave per edge, lane = feature ----------------

__global__ __launch_bounds__(256) void k_scatter64(const float* __restrict__ H,
                                                   const int* __restrict__ src,
                                                   const int* __restrict__ dst,
                                                   const float* __restrict__ dis,
                                                   float* __restrict__ Agg, int E) {
    int lane = threadIdx.x & 63;
    int wave = (blockIdx.x * 256 + threadIdx.x) >> 6;
    int nwaves = (gridDim.x * 256) >> 6;
    for (int e = wave; e < E; e += nwaves) {
        int s = src[e], d = dst[e];
        float norm = dis[s] * dis[d];
        float v = H[s * 64 + lane] * norm;
        atomicAdd(&Agg[d * 64 + lane], v);
    }
}

__global__ __launch_bounds__(256) void k_relu(float* __restrict__ A, int n) {
    int i = blockIdx.x * 256 + threadIdx.x;
    if (i < n) A[i] = fmaxf(A[i], 0.0f);
}

// ---------------- layer 3: col[i] = H[i,:]·W3 ; out[i] = col*dis^2 + b3 ----------------

__global__ __launch_bounds__(256) void k_mm1col(const float* __restrict__ H,
                                                const float* __restrict__ W3,
                                                const float* __restrict__ b3,
                                                const float* __restrict__ dis,
                                                float* __restrict__ col,
                                                float* __restrict__ out, int N) {
    int lane = threadIdx.x & 63;
    int node = (blockIdx.x * 256 + threadIdx.x) >> 6;
    if (node >= N) return;
    float v = H[node * 64 + lane] * W3[lane];
#pragma unroll
    for (int off = 32; off >= 1; off >>= 1) v += __shfl_down(v, off);
    if (lane == 0) {
        float d = dis[node];
        col[node] = v;
        out[node] = v * d * d + b3[0];
    }
}

__global__ __launch_bounds__(256) void k_scatter1(const float* __restrict__ col,
                                                  const int* __restrict__ src,
                                                  const int* __restrict__ dst,
                                                  const float* __restrict__ dis,
                                                  float* __restrict__ out, int E) {
    int e = blockIdx.x * 256 + threadIdx.x;
    if (e < E) {
        int s = src[e], d = dst[e];
        atomicAdd(&out[d], col[s] * dis[s] * dis[d]);
    }
}

extern "C" void kernel_launch(void* const* d_in, const int* in_sizes, int n_in,
                              void* d_out, int out_size, void* d_ws, size_t ws_size,
                              hipStream_t stream) {
    const float* x  = (const float*)d_in[0];
    const int*   ei = (const int*)d_in[1];
    const float* W1 = (const float*)d_in[2];
    const float* b1 = (const float*)d_in[3];
    const float* W2 = (const float*)d_in[4];
    const float* b2 = (const float*)d_in[5];
    const float* W3 = (const float*)d_in[6];
    const float* b3 = (const float*)d_in[7];
    float* out = (float*)d_out;

    const int N = in_sizes[0] / IN_DIM;     // 100000
    const int E = in_sizes[1] / 2;          // 1600000
    const int* src = ei;
    const int* dst = ei + E;

    // workspace layout (floats)
    float* ws   = (float*)d_ws;
    float* dis  = ws;                        // N        (also deg scratch)
    float* bufA = ws + 102400;               // N*64
    float* bufB = bufA + (size_t)N * 64;     // N*64
    float* col  = bufB + (size_t)N * 64;     // N

    const int NB_N   = (N + 255) / 256;
    const int NB_NF  = (N * 64 + 255) / 256;
    const int NB_E   = (E + 255) / 256;
    const int NB_MM  = (N + 3) / 4;
    const int NB_SC  = 25000;                // grid-stride scatter waves
    const int NB_WV  = (N * 64 + 255) / 256; // wave-per-node kernels

    // deg -> dis
    hipMemsetAsync(dis, 0, (size_t)N * sizeof(float), stream);
    k_deg<<<NB_E, 256, 0, stream>>>(dst, dis, E);
    k_dis<<<NB_N, 256, 0, stream>>>(dis, N);

    // ---- layer 1 ----
    k_mm64<IN_DIM><<<NB_MM, 256, 0, stream>>>(x, W1, bufA, N);
    k_self_init<<<NB_NF, 256, 0, stream>>>(bufA, dis, b1, bufB, N);
    k_scatter64<<<NB_SC, 256, 0, stream>>>(bufA, src, dst, dis, bufB, E);
    k_relu<<<NB_NF, 256, 0, stream>>>(bufB, N * 64);

    // ---- layer 2 ----
    k_mm64<HID><<<NB_MM, 256, 0, stream>>>(bufB, W2, bufA, N);
    k_self_init<<<NB_NF, 256, 0, stream>>>(bufA, dis, b2, bufB, N);
    k_scatter64<<<NB_SC, 256, 0, stream>>>(bufA, src, dst, dis, bufB, E);
    k_relu<<<NB_NF, 256, 0, stream>>>(bufB, N * 64);

    // ---- layer 3 (OUT_DIM = 1) ----
    k_mm1col<<<NB_WV, 256, 0, stream>>>(bufB, W3, b3, dis, col, out, N);
    k_scatter1<<<NB_E, 256, 0, stream>>>(col, src, dst, dis, out, E);
}

// Round 2
// 566.910 us; speedup vs baseline: 1.9977x; 1.9977x over previous
//
#include <hip/hip_runtime.h>

#define IN_DIM 128
#define HID 64

// ---------------- histogram of dst ----------------
__global__ __launch_bounds__(256) void k_hist(const int* __restrict__ dst,
                                              int* __restrict__ cnt, int E) {
    int e = blockIdx.x * 256 + threadIdx.x;
    if (e < E) atomicAdd(&cnt[dst[e]], 1);
}

// ---------------- dis = rsqrt(1 + deg) ----------------
__global__ __launch_bounds__(256) void k_dis(const int* __restrict__ cnt,
                                             float* __restrict__ dis, int N) {
    int i = blockIdx.x * 256 + threadIdx.x;
    if (i < N) dis[i] = rsqrtf((float)cnt[i] + 1.0f);
}

// ---------------- exclusive scan (3-kernel classic) ----------------
__global__ __launch_bounds__(256) void k_scan_block(const int* __restrict__ cnt,
                                                    int* __restrict__ partial,
                                                    int* __restrict__ blockSums, int N) {
    __shared__ int tmp[256];
    int i = blockIdx.x * 256 + threadIdx.x;
    int v = (i < N) ? cnt[i] : 0;
    tmp[threadIdx.x] = v;
    __syncthreads();
    for (int off = 1; off < 256; off <<= 1) {
        int t = (threadIdx.x >= off) ? tmp[threadIdx.x - off] : 0;
        __syncthreads();
        tmp[threadIdx.x] += t;
        __syncthreads();
    }
    int incl = tmp[threadIdx.x];
    if (i < N) partial[i] = incl - v;           // exclusive
    if (threadIdx.x == 255) blockSums[blockIdx.x] = incl;
}

__global__ __launch_bounds__(512) void k_scan_sums(int* __restrict__ blockSums, int nB) {
    __shared__ int tmp[512];
    int t = threadIdx.x;
    int v = (t < nB) ? blockSums[t] : 0;
    tmp[t] = v;
    __syncthreads();
    for (int off = 1; off < 512; off <<= 1) {
        int a = (t >= off) ? tmp[t - off] : 0;
        __syncthreads();
        tmp[t] += a;
        __syncthreads();
    }
    int incl = tmp[t];
    __syncthreads();
    if (t < nB) blockSums[t] = incl - v;        // exclusive, in place
}

__global__ __launch_bounds__(256) void k_scan_add(const int* __restrict__ partial,
                                                  const int* __restrict__ blockOff,
                                                  int* __restrict__ rowStart,
                                                  int* __restrict__ cursor, int N, int E) {
    int i = blockIdx.x * 256 + threadIdx.x;
    if (i < N) {
        int rs = partial[i] + blockOff[i >> 8];
        rowStart[i] = rs;
        cursor[i] = rs;
    } else if (i == N) {
        rowStart[N] = E;
    }
}

// ---------------- edge placement: dst-bucketed src + precomputed norm ----------------
__global__ __launch_bounds__(256) void k_build(const int* __restrict__ src,
                                               const int* __restrict__ dst,
                                               const float* __restrict__ dis,
                                               int* __restrict__ cursor,
                                               int* __restrict__ esrc,
                                               float* __restrict__ enorm, int E) {
    int e = blockIdx.x * 256 + threadIdx.x;
    if (e >= E) return;
    int s = src[e], d = dst[e];
    int pos = atomicAdd(&cursor[d], 1);
    esrc[pos] = s;
    enorm[pos] = dis[s] * dis[d];
}

// ---------------- dense transform: H[N,64] = X[N,K] @ W[K,64] ----------------
template <int K>
__global__ __launch_bounds__(256) void k_mm64(const float* __restrict__ X,
                                              const float* __restrict__ W,
                                              float* __restrict__ H, int N) {
    __shared__ float Ws[K * 64];
    __shared__ float Xs[4][K];
    for (int i = threadIdx.x; i < K * 64; i += 256) Ws[i] = W[i];
    int row0 = blockIdx.x * 4;
    for (int i = threadIdx.x; i < 4 * K; i += 256) {
        int r = i / K, k = i - r * K;
        int row = row0 + r;
        Xs[r][k] = (row < N) ? X[row * K + k] : 0.0f;
    }
    __syncthreads();
    int r = threadIdx.x >> 6;
    int c = threadIdx.x & 63;
    int row = row0 + r;
    if (row >= N) return;
    float acc = 0.0f;
#pragma unroll
    for (int k = 0; k < K; ++k) acc += Xs[r][k] * Ws[k * 64 + c];
    H[row * 64 + c] = acc;
}

// ---------------- gather-aggregate: wave per node, lane = feature ----------------
// out[i,:] = (relu of) b + H[i,:]*dis[i]^2 + sum_{e in CSR[i]} H[esrc[e],:]*enorm[e]
__global__ __launch_bounds__(256) void k_gather64(const float* __restrict__ H,
                                                  const int* __restrict__ esrc,
                                                  const float* __restrict__ enorm,
                                                  const int* __restrict__ rowStart,
                                                  const float* __restrict__ dis,
                                                  const float* __restrict__ b,
                                                  float* __restrict__ out,
                                                  int N, int doRelu) {
    int lane = threadIdx.x & 63;
    int node = (blockIdx.x * 256 + threadIdx.x) >> 6;
    if (node >= N) return;
    int r0 = rowStart[node], r1 = rowStart[node + 1];
    float d = dis[node];
    float acc = H[(size_t)node * 64 + lane] * d * d + b[lane];

    for (int base = r0; base < r1; base += 64) {
        int cnt = min(64, r1 - base);
        int s  = (lane < cnt) ? esrc[base + lane] : 0;
        float nm = (lane < cnt) ? enorm[base + lane] : 0.0f;
        int j = 0;
        for (; j + 4 <= cnt; j += 4) {
            int s0 = __shfl(s, j, 64),     s1 = __shfl(s, j + 1, 64);
            int s2 = __shfl(s, j + 2, 64), s3 = __shfl(s, j + 3, 64);
            float n0 = __shfl(nm, j, 64),     n1 = __shfl(nm, j + 1, 64);
            float n2 = __shfl(nm, j + 2, 64), n3 = __shfl(nm, j + 3, 64);
            float h0 = H[(size_t)s0 * 64 + lane];
            float h1 = H[(size_t)s1 * 64 + lane];
            float h2 = H[(size_t)s2 * 64 + lane];
            float h3 = H[(size_t)s3 * 64 + lane];
            acc += h0 * n0;
            acc += h1 * n1;
            acc += h2 * n2;
            acc += h3 * n3;
        }
        for (; j < cnt; ++j) {
            int sj = __shfl(s, j, 64);
            float nj = __shfl(nm, j, 64);
            acc += H[(size_t)sj * 64 + lane] * nj;
        }
    }
    if (doRelu) acc = fmaxf(acc, 0.0f);
    out[(size_t)node * 64 + lane] = acc;
}

// ---------------- layer 3: col[i] = H[i,:]·W3 ; out[i] = col*dis^2 + b3 ----------------
__global__ __launch_bounds__(256) void k_mm1col(const float* __restrict__ H,
                                                const float* __restrict__ W3,
                                                const float* __restrict__ b3,
                                                const float* __restrict__ dis,
                                                float* __restrict__ col,
                                                float* __restrict__ out, int N) {
    int lane = threadIdx.x & 63;
    int node = (blockIdx.x * 256 + threadIdx.x) >> 6;
    if (node >= N) return;
    float v = H[(size_t)node * 64 + lane] * W3[lane];
#pragma unroll
    for (int off = 32; off >= 1; off >>= 1) v += __shfl_down(v, off, 64);
    if (lane == 0) {
        float d = dis[node];
        col[node] = v;
        out[node] = v * d * d + b3[0];
    }
}

__global__ __launch_bounds__(256) void k_gather1(const float* __restrict__ col,
                                                 const int* __restrict__ esrc,
                                                 const float* __restrict__ enorm,
                                                 const int* __restrict__ rowStart,
                                                 float* __restrict__ out, int N) {
    int i = blockIdx.x * 256 + threadIdx.x;
    if (i >= N) return;
    int r0 = rowStart[i], r1 = rowStart[i + 1];
    float acc = 0.0f;
    for (int e = r0; e < r1; ++e) acc += col[esrc[e]] * enorm[e];
    out[i] += acc;
}

extern "C" void kernel_launch(void* const* d_in, const int* in_sizes, int n_in,
                              void* d_out, int out_size, void* d_ws, size_t ws_size,
                              hipStream_t stream) {
    const float* x  = (const float*)d_in[0];
    const int*   ei = (const int*)d_in[1];
    const float* W1 = (const float*)d_in[2];
    const float* b1 = (const float*)d_in[3];
    const float* W2 = (const float*)d_in[4];
    const float* b2 = (const float*)d_in[5];
    const float* W3 = (const float*)d_in[6];
    const float* b3 = (const float*)d_in[7];
    float* out = (float*)d_out;

    const int N = in_sizes[0] / IN_DIM;     // 100000
    const int E = in_sizes[1] / 2;          // 1600000
    const int* src = ei;
    const int* dst = ei + E;

    // ---- workspace layout (byte offsets, 1 KiB aligned) ----
    char* w = (char*)d_ws;
    auto alloc = [&](size_t bytes) {
        char* p = w;
        w += (bytes + 1023) & ~(size_t)1023;
        return p;
    };
    float* dis      = (float*)alloc((size_t)N * 4);
    float* bufA     = (float*)alloc((size_t)N * 64 * 4);
    float* bufB     = (float*)alloc((size_t)N * 64 * 4);
    float* col      = (float*)alloc((size_t)N * 4);
    int*   cnt      = (int*)alloc((size_t)N * 4);
    int*   partial  = (int*)alloc((size_t)N * 4);
    int*   rowStart = (int*)alloc((size_t)(N + 1) * 4);
    int*   cursor   = (int*)alloc((size_t)N * 4);
    int*   blockSums= (int*)alloc((size_t)512 * 4);
    int*   esrc     = (int*)alloc((size_t)E * 4);
    float* enorm    = (float*)alloc((size_t)E * 4);

    const int NB_N  = (N + 255) / 256;       // node-per-thread kernels
    const int NB_N1 = (N + 1 + 255) / 256;   // scan_add covers N+1
    const int NB_E  = (E + 255) / 256;
    const int NB_MM = (N + 3) / 4;
    const int NB_WV = (N * 64 + 255) / 256;  // wave-per-node kernels
    const int nB    = NB_N;                  // scan blocks (391)

    // ---- CSR build (amortized over all 3 aggregations) ----
    hipMemsetAsync(cnt, 0, (size_t)N * sizeof(int), stream);
    k_hist<<<NB_E, 256, 0, stream>>>(dst, cnt, E);
    k_dis<<<NB_N, 256, 0, stream>>>(cnt, dis, N);
    k_scan_block<<<nB, 256, 0, stream>>>(cnt, partial, blockSums, N);
    k_scan_sums<<<1, 512, 0, stream>>>(blockSums, nB);
    k_scan_add<<<NB_N1, 256, 0, stream>>>(partial, blockSums, rowStart, cursor, N, E);
    k_build<<<NB_E, 256, 0, stream>>>(src, dst, dis, cursor, esrc, enorm, E);

    // ---- layer 1 ----
    k_mm64<IN_DIM><<<NB_MM, 256, 0, stream>>>(x, W1, bufA, N);
    k_gather64<<<NB_WV, 256, 0, stream>>>(bufA, esrc, enorm, rowStart, dis, b1, bufB, N, 1);

    // ---- layer 2 ----
    k_mm64<HID><<<NB_MM, 256, 0, stream>>>(bufB, W2, bufA, N);
    k_gather64<<<NB_WV, 256, 0, stream>>>(bufA, esrc, enorm, rowStart, dis, b2, bufB, N, 1);

    // ---- layer 3 (OUT_DIM = 1) ----
    k_mm1col<<<NB_WV, 256, 0, stream>>>(bufB, W3, b3, dis, col, out, N);
    k_gather1<<<NB_N, 256, 0, stream>>>(col, esrc, enorm, rowStart, out, N);
}

// Round 3
// 443.675 us; speedup vs baseline: 2.5526x; 1.2778x over previous
//
#include <hip/hip_runtime.h>

#define IN_DIM 128
#define HID 64

// ---------------- histogram of dst ----------------
__global__ __launch_bounds__(256) void k_hist(const int* __restrict__ dst,
                                              int* __restrict__ cnt, int E) {
    int e = blockIdx.x * 256 + threadIdx.x;
    if (e < E) atomicAdd(&cnt[dst[e]], 1);
}

// ---------------- dis = rsqrt(1 + deg) ----------------
__global__ __launch_bounds__(256) void k_dis(const int* __restrict__ cnt,
                                             float* __restrict__ dis, int N) {
    int i = blockIdx.x * 256 + threadIdx.x;
    if (i < N) dis[i] = rsqrtf((float)cnt[i] + 1.0f);
}

// ---------------- exclusive scan (3-kernel classic) ----------------
__global__ __launch_bounds__(256) void k_scan_block(const int* __restrict__ cnt,
                                                    int* __restrict__ partial,
                                                    int* __restrict__ blockSums, int N) {
    __shared__ int tmp[256];
    int i = blockIdx.x * 256 + threadIdx.x;
    int v = (i < N) ? cnt[i] : 0;
    tmp[threadIdx.x] = v;
    __syncthreads();
    for (int off = 1; off < 256; off <<= 1) {
        int t = (threadIdx.x >= off) ? tmp[threadIdx.x - off] : 0;
        __syncthreads();
        tmp[threadIdx.x] += t;
        __syncthreads();
    }
    int incl = tmp[threadIdx.x];
    if (i < N) partial[i] = incl - v;           // exclusive
    if (threadIdx.x == 255) blockSums[blockIdx.x] = incl;
}

__global__ __launch_bounds__(512) void k_scan_sums(int* __restrict__ blockSums, int nB) {
    __shared__ int tmp[512];
    int t = threadIdx.x;
    int v = (t < nB) ? blockSums[t] : 0;
    tmp[t] = v;
    __syncthreads();
    for (int off = 1; off < 512; off <<= 1) {
        int a = (t >= off) ? tmp[t - off] : 0;
        __syncthreads();
        tmp[t] += a;
        __syncthreads();
    }
    int incl = tmp[t];
    __syncthreads();
    if (t < nB) blockSums[t] = incl - v;        // exclusive, in place
}

__global__ __launch_bounds__(256) void k_scan_add(const int* __restrict__ partial,
                                                  const int* __restrict__ blockOff,
                                                  int* __restrict__ rowStart,
                                                  int* __restrict__ cursor, int N, int E) {
    int i = blockIdx.x * 256 + threadIdx.x;
    if (i < N) {
        int rs = partial[i] + blockOff[i >> 8];
        rowStart[i] = rs;
        cursor[i] = rs;
    } else if (i == N) {
        rowStart[N] = E;
    }
}

// ---------------- edge placement: packed {src, norm} per edge ----------------
__global__ __launch_bounds__(256) void k_build(const int* __restrict__ src,
                                               const int* __restrict__ dst,
                                               const float* __restrict__ dis,
                                               int* __restrict__ cursor,
                                               int2* __restrict__ epk, int E) {
    int e = blockIdx.x * 256 + threadIdx.x;
    if (e >= E) return;
    int s = src[e], d = dst[e];
    int pos = atomicAdd(&cursor[d], 1);
    int2 pk;
    pk.x = s;
    pk.y = __float_as_int(dis[s] * dis[d]);
    epk[pos] = pk;      // single 8B random store per edge
}

// ---------------- register-tiled transform: H[N,64] = X[N,K] @ W[K,64] ----------------
// block: 128 rows x 64 cols, 256 threads, each thread 8x4 register tile.
template <int K>
__global__ __launch_bounds__(256) void k_mmrt(const float* __restrict__ X,
                                              const float* __restrict__ W,
                                              float* __restrict__ H, int N) {
    constexpr int BR = 128, BK = 32, S = 132;   // S%4==0 (16B b128 align), conflict-free reads
    __shared__ float Xs[BK * S];                 // Xs[k][row]
    __shared__ float Ws[BK * 64];                // Ws[k][c]
    const int tid = threadIdx.x;
    const int c0 = (tid & 15) * 4;
    const int row0 = (tid >> 4) * 8;
    const int blockRow = blockIdx.x * BR;
    float acc[8][4];
#pragma unroll
    for (int r = 0; r < 8; ++r)
#pragma unroll
        for (int c = 0; c < 4; ++c) acc[r][c] = 0.f;

    for (int k0 = 0; k0 < K; k0 += BK) {
        // X tile (128 rows x 32 k), transposed store into Xs
        int i = tid;
#pragma unroll
        for (int it = 0; it < 4; ++it, i += 256) {
            int row = i >> 3, kq = i & 7;
            int gr = blockRow + row;
            if (gr >= N) gr = N - 1;
            float4 v = *(const float4*)&X[(size_t)gr * K + k0 + kq * 4];
            Xs[(kq * 4 + 0) * S + row] = v.x;
            Xs[(kq * 4 + 1) * S + row] = v.y;
            Xs[(kq * 4 + 2) * S + row] = v.z;
            Xs[(kq * 4 + 3) * S + row] = v.w;
        }
        // W tile (32 k x 64 c)
        int j2 = tid;
#pragma unroll
        for (int it = 0; it < 2; ++it, j2 += 256) {
            int k = j2 >> 4, cq = j2 & 15;
            *(float4*)&Ws[k * 64 + cq * 4] =
                *(const float4*)&W[(size_t)(k0 + k) * 64 + cq * 4];
        }
        __syncthreads();
#pragma unroll
        for (int kk = 0; kk < BK; kk += 4) {
            float4 b[4], alo[4], ahi[4];
#pragma unroll
            for (int j = 0; j < 4; ++j) {
                b[j]   = *(const float4*)&Ws[(kk + j) * 64 + c0];
                alo[j] = *(const float4*)&Xs[(kk + j) * S + row0];
                ahi[j] = *(const float4*)&Xs[(kk + j) * S + row0 + 4];
            }
#pragma unroll
            for (int j = 0; j < 4; ++j) {
                const float a_[8] = {alo[j].x, alo[j].y, alo[j].z, alo[j].w,
                                     ahi[j].x, ahi[j].y, ahi[j].z, ahi[j].w};
#pragma unroll
                for (int r = 0; r < 8; ++r) {
                    acc[r][0] += a_[r] * b[j].x;
                    acc[r][1] += a_[r] * b[j].y;
                    acc[r][2] += a_[r] * b[j].z;
                    acc[r][3] += a_[r] * b[j].w;
                }
            }
        }
        __syncthreads();
    }
#pragma unroll
    for (int r = 0; r < 8; ++r) {
        int gr = blockRow + row0 + r;
        if (gr < N) *(float4*)&H[(size_t)gr * 64 + c0] = *(float4*)&acc[r][0];
    }
}

// ---------------- gather-aggregate: wave per node, lane = feature ----------------
__global__ __launch_bounds__(256) void k_gather64(const float* __restrict__ H,
                                                  const int2* __restrict__ epk,
                                                  const int* __restrict__ rowStart,
                                                  const float* __restrict__ dis,
                                                  const float* __restrict__ b,
                                                  float* __restrict__ out,
                                                  int N, int doRelu) {
    int lane = threadIdx.x & 63;
    int node = (blockIdx.x * 256 + threadIdx.x) >> 6;
    if (node >= N) return;
    int r0 = rowStart[node], r1 = rowStart[node + 1];
    float d = dis[node];
    float acc = H[(size_t)node * 64 + lane] * d * d + b[lane];

    for (int base = r0; base < r1; base += 64) {
        int cnt = min(64, r1 - base);
        int2 pk = (lane < cnt) ? epk[base + lane] : make_int2(0, 0);
        int s = pk.x;
        float nm = __int_as_float(pk.y);
        int j = 0;
        for (; j + 4 <= cnt; j += 4) {
            int s0 = __shfl(s, j, 64),     s1 = __shfl(s, j + 1, 64);
            int s2 = __shfl(s, j + 2, 64), s3 = __shfl(s, j + 3, 64);
            float n0 = __shfl(nm, j, 64),     n1 = __shfl(nm, j + 1, 64);
            float n2 = __shfl(nm, j + 2, 64), n3 = __shfl(nm, j + 3, 64);
            float h0 = H[(size_t)s0 * 64 + lane];
            float h1 = H[(size_t)s1 * 64 + lane];
            float h2 = H[(size_t)s2 * 64 + lane];
            float h3 = H[(size_t)s3 * 64 + lane];
            acc += h0 * n0;
            acc += h1 * n1;
            acc += h2 * n2;
            acc += h3 * n3;
        }
        for (; j < cnt; ++j) {
            int sj = __shfl(s, j, 64);
            float nj = __shfl(nm, j, 64);
            acc += H[(size_t)sj * 64 + lane] * nj;
        }
    }
    if (doRelu) acc = fmaxf(acc, 0.0f);
    out[(size_t)node * 64 + lane] = acc;
}

// ---------------- layer 3: col[i] = H[i,:]·W3 ; out[i] = col*dis^2 + b3 ----------------
__global__ __launch_bounds__(256) void k_mm1col(const float* __restrict__ H,
                                                const float* __restrict__ W3,
                                                const float* __restrict__ b3,
                                                const float* __restrict__ dis,
                                                float* __restrict__ col,
                                                float* __restrict__ out, int N) {
    int lane = threadIdx.x & 63;
    int node = (blockIdx.x * 256 + threadIdx.x) >> 6;
    if (node >= N) return;
    float v = H[(size_t)node * 64 + lane] * W3[lane];
#pragma unroll
    for (int off = 32; off >= 1; off >>= 1) v += __shfl_down(v, off, 64);
    if (lane == 0) {
        float d = dis[node];
        col[node] = v;
        out[node] = v * d * d + b3[0];
    }
}

__global__ __launch_bounds__(256) void k_gather1(const float* __restrict__ col,
                                                 const int2* __restrict__ epk,
                                                 const int* __restrict__ rowStart,
                                                 float* __restrict__ out, int N) {
    int i = blockIdx.x * 256 + threadIdx.x;
    if (i >= N) return;
    int r0 = rowStart[i], r1 = rowStart[i + 1];
    float acc = 0.0f;
    for (int e = r0; e < r1; ++e) {
        int2 pk = epk[e];
        acc += col[pk.x] * __int_as_float(pk.y);
    }
    out[i] += acc;
}

extern "C" void kernel_launch(void* const* d_in, const int* in_sizes, int n_in,
                              void* d_out, int out_size, void* d_ws, size_t ws_size,
                              hipStream_t stream) {
    const float* x  = (const float*)d_in[0];
    const int*   ei = (const int*)d_in[1];
    const float* W1 = (const float*)d_in[2];
    const float* b1 = (const float*)d_in[3];
    const float* W2 = (const float*)d_in[4];
    const float* b2 = (const float*)d_in[5];
    const float* W3 = (const float*)d_in[6];
    const float* b3 = (const float*)d_in[7];
    float* out = (float*)d_out;

    const int N = in_sizes[0] / IN_DIM;     // 100000
    const int E = in_sizes[1] / 2;          // 1600000
    const int* src = ei;
    const int* dst = ei + E;

    // ---- workspace layout (byte offsets, 1 KiB aligned) ----
    char* w = (char*)d_ws;
    auto alloc = [&](size_t bytes) {
        char* p = w;
        w += (bytes + 1023) & ~(size_t)1023;
        return p;
    };
    float* dis      = (float*)alloc((size_t)N * 4);
    float* bufA     = (float*)alloc((size_t)N * 64 * 4);
    float* bufB     = (float*)alloc((size_t)N * 64 * 4);
    float* col      = (float*)alloc((size_t)N * 4);
    int*   cnt      = (int*)alloc((size_t)N * 4);
    int*   partial  = (int*)alloc((size_t)N * 4);
    int*   rowStart = (int*)alloc((size_t)(N + 1) * 4);
    int*   cursor   = (int*)alloc((size_t)N * 4);
    int*   blockSums= (int*)alloc((size_t)512 * 4);
    int2*  epk      = (int2*)alloc((size_t)E * 8);

    const int NB_N  = (N + 255) / 256;
    const int NB_N1 = (N + 1 + 255) / 256;
    const int NB_E  = (E + 255) / 256;
    const int NB_MM = (N + 127) / 128;
    const int NB_WV = (N * 64 + 255) / 256;
    const int nB    = NB_N;

    // ---- CSR build ----
    hipMemsetAsync(cnt, 0, (size_t)N * sizeof(int), stream);
    k_hist<<<NB_E, 256, 0, stream>>>(dst, cnt, E);
    k_dis<<<NB_N, 256, 0, stream>>>(cnt, dis, N);
    k_scan_block<<<nB, 256, 0, stream>>>(cnt, partial, blockSums, N);
    k_scan_sums<<<1, 512, 0, stream>>>(blockSums, nB);
    k_scan_add<<<NB_N1, 256, 0, stream>>>(partial, blockSums, rowStart, cursor, N, E);
    k_build<<<NB_E, 256, 0, stream>>>(src, dst, dis, cursor, epk, E);

    // ---- layer 1 ----
    k_mmrt<IN_DIM><<<NB_MM, 256, 0, stream>>>(x, W1, bufA, N);
    k_gather64<<<NB_WV, 256, 0, stream>>>(bufA, epk, rowStart, dis, b1, bufB, N, 1);

    // ---- layer 2 ----
    k_mmrt<HID><<<NB_MM, 256, 0, stream>>>(bufB, W2, bufA, N);
    k_gather64<<<NB_WV, 256, 0, stream>>>(bufA, epk, rowStart, dis, b2, bufB, N, 1);

    // ---- layer 3 (OUT_DIM = 1) ----
    k_mm1col<<<NB_WV, 256, 0, stream>>>(bufB, W3, b3, dis, col, out, N);
    k_gather1<<<NB_N, 256, 0, stream>>>(col, epk, rowStart, out, N);
}